// Round 15
// baseline (111.956 us; speedup 1.0000x reference)
//
#include <hip/hip_runtime.h>
#include <math.h>

#define B 512
#define T 256
#define N 200
#define H 64
#define TN (T*N)     // 51200
#define NT 1024      // 16 waves -> 4 waves/SIMD

#define ARS 232              // A image row stride in bf16 (464 B)
#define XTRS 80              // Xt row stride bytes (32 bf16 + 16B pad; 5 slots, odd -> skew)

// ---- LDS map (byte offsets), liveness-sequenced (proven r9-r14) ----
#define LS_XT(i) (102400 + 16000*(i))   // 2 x [200 n][32 t] bf16 stride 80
#define LS_MUS   92800                  // 800 f32 mu partials
#define LS_VARA  96000                  // 200 f32 raw diag
#define LS_MUA   96800
#define LS_RSA   97600                  // ..98400
#define LS_YT    92800                  // 64 x 464 B  (pads zeroed AFTER stats die)
#define LS_BUF2  122496                 // 64 x 464 B  (W1T, then h; overlaps dead Xt1)
#define LS_W2T   152192                 // 64 x 144 B  (staged ONCE, never overwritten)
#define LS_DINV  161408                 // 200 f32 (per-sample)
#define LS_B1    162208
#define LS_B2    162464
#define LS_SZ    162720

typedef short short8 __attribute__((ext_vector_type(8)));
typedef float f32x16 __attribute__((ext_vector_type(16)));

__device__ __forceinline__ unsigned bf16r(float x) {
    unsigned u = __float_as_uint(x);
    return (u + 0x7fffu + ((u >> 16) & 1u)) >> 16;   // round-to-nearest-even
}
__device__ __forceinline__ float bf2f(unsigned short u) {
    return __uint_as_float(((unsigned)u) << 16);
}

// LDS-only barrier: does NOT drain vmcnt, so global prefetch loads issued
// before it stay in flight (a __syncthreads here would re-serialize the
// cross-sample pipeline). All cross-wave deps in these phases are LDS.
#define BAR_LDS() do { \
    asm volatile("s_waitcnt lgkmcnt(0)" ::: "memory"); \
    __builtin_amdgcn_sched_barrier(0); \
    __builtin_amdgcn_s_barrier(); \
    __builtin_amdgcn_sched_barrier(0); } while (0)

__global__ __launch_bounds__(NT) void k_fused(const float* __restrict__ data,
                                              const float* __restrict__ W1,
                                              const float* __restrict__ b1f,
                                              const float* __restrict__ W2,
                                              const float* __restrict__ b2f,
                                              float* __restrict__ out) {
    __shared__ __align__(16) unsigned char LDS[LS_SZ];
    const int tid  = threadIdx.x;
    const int blk  = blockIdx.x;        // grid = 256; block handles samples 2*blk, 2*blk+1
    const int lane = tid & 63;
    const int wid  = tid >> 6;          // 0..15
    const int l31  = lane & 31;
    const int hi32 = lane >> 5;

    float w1r[13], w2r[4];              // weight prefetch (persists across both samples)
    float rA[8], rB[8];                 // register chunk buffers (no LDS staging)
    const int n0 = tid % 200, q0 = tid / 200;   // transpose unit (tid<800 only)

    // ---- corr tile assignment: 28 upper-tri tiles = 12 A-sharing pairs + 4 singles ----
    int ti, tj0_; bool dual;
    if      (wid == 0)  { ti = 0; tj0_ = 0; dual = true;  }
    else if (wid == 1)  { ti = 0; tj0_ = 2; dual = true;  }
    else if (wid == 2)  { ti = 0; tj0_ = 4; dual = true;  }
    else if (wid == 3)  { ti = 1; tj0_ = 1; dual = true;  }
    else if (wid == 4)  { ti = 1; tj0_ = 3; dual = true;  }
    else if (wid == 5)  { ti = 1; tj0_ = 5; dual = true;  }
    else if (wid == 6)  { ti = 2; tj0_ = 2; dual = true;  }
    else if (wid == 7)  { ti = 2; tj0_ = 4; dual = true;  }
    else if (wid == 8)  { ti = 3; tj0_ = 3; dual = true;  }
    else if (wid == 9)  { ti = 3; tj0_ = 5; dual = true;  }
    else if (wid == 10) { ti = 4; tj0_ = 4; dual = true;  }
    else if (wid == 11) { ti = 5; tj0_ = 5; dual = true;  }
    else if (wid == 12) { ti = 0; tj0_ = 6; dual = false; }
    else if (wid == 13) { ti = 2; tj0_ = 6; dual = false; }
    else if (wid == 14) { ti = 4; tj0_ = 6; dual = false; }
    else                { ti = 6; tj0_ = 6; dual = false; }
    const int tj1_ = tj0_ + 1;
    const bool diag0 = (ti == tj0_);
    int arow = ti * 32 + l31;   if (arow > 199) arow = 199;
    int bc0  = tj0_ * 32 + l31; if (bc0 > 199)  bc0 = 199;
    int bc1  = tj1_ * 32 + l31; if (bc1 > 199)  bc1 = 199;

    // load chunk cc of a sample straight into registers (8 coalesced b32/thread)
    auto ldchunk = [&](const float* base, int cc, float* r) {
        if (tid < 800) {
            const float* src = base + (cc * 32 + q0 * 8) * 200 + n0;
#pragma unroll
            for (int j = 0; j < 8; ++j) r[j] = src[j * 200];
        }
    };

    const float* db0 = data + (size_t)(2 * blk) * TN;
    ldchunk(db0, 0, rA); ldchunk(db0, 1, rB);

    for (int s = 0; s < 2; ++s) {
        const float* dbase = data + (size_t)(2 * blk + s) * TN;
        const float* dnext = dbase + TN;                   // sample s+1 (s==0 only)
        float* obase = out + (size_t)(2 * blk + s) * N * H;

        f32x16 acc0 = {}, acc1 = {};
        float mu0 = 0.f;

        auto pack = [&](int c, const float* r) {
            if (tid < 800) {
                unsigned u[4]; float a = 0.f;
#pragma unroll
                for (int j = 0; j < 4; ++j) {
                    unsigned b0 = bf16r(r[2 * j]);
                    unsigned b1 = bf16r(r[2 * j + 1]);
                    a += bf2f((unsigned short)b0) + bf2f((unsigned short)b1);
                    u[j] = b0 | (b1 << 16);
                }
                mu0 += a;
                uint4 pk; pk.x = u[0]; pk.y = u[1]; pk.z = u[2]; pk.w = u[3];
                *(uint4*)(LDS + LS_XT(c & 1) + n0 * XTRS + q0 * 16) = pk;
            }
        };
        auto domfma = [&](int cp) {
            const unsigned char* Xp = LDS + LS_XT(cp & 1);
#pragma unroll
            for (int kc = 0; kc < 2; ++kc) {
                int kb = kc * 32 + hi32 * 16;
                short8 a = *(const short8*)(Xp + arow * XTRS + kb);
                short8 b0 = diag0 ? a : *(const short8*)(Xp + bc0 * XTRS + kb);
                acc0 = __builtin_amdgcn_mfma_f32_32x32x16_bf16(a, b0, acc0, 0, 0, 0);
                if (dual) {
                    short8 b1 = *(const short8*)(Xp + bc1 * XTRS + kb);
                    acc1 = __builtin_amdgcn_mfma_f32_32x32x16_bf16(a, b1, acc1, 0, 0, 0);
                }
            }
        };

        // ---- corr K-loop: ONE barrier/chunk; region = {pack(c); issue(c+2); mfma(c)} ----
        for (int c = 0; c < 8; ++c) {
            if (c & 1) pack(c, rB); else pack(c, rA);
            if (c < 6) { if (c & 1) ldchunk(dbase, c + 2, rB); else ldchunk(dbase, c + 2, rA); }
            if (s == 0 && c == 7) {          // weight prefetch: once, overlaps mfma(7)+tail
#pragma unroll
                for (int i = 0; i < 12; ++i) w1r[i] = W1[tid + i * 1024];
                if (tid < 512) w1r[12] = W1[tid + 12288];
#pragma unroll
                for (int i = 0; i < 4; ++i) w2r[i] = W2[tid + i * 1024];
            }
            BAR_LDS();                       // publish Xt[c&1]
            domfma(c);
        }
        BAR_LDS();                           // Xt dead -> BUF2 (overlaps Xt1) writable

        // ---- weight staging (from regs) + mu partials + raw diag ----
#pragma unroll
        for (int i = 0; i < 13; ++i) {       // W1T -> BUF2 (re-staged per sample: BUF2
            int e = tid + i * 1024;          // is overwritten by h during G2)
            if (i < 12 || tid < 512) {
                int k = e >> 6, l = e & 63;
                *(unsigned short*)(LDS + LS_BUF2 + l * 464 + k * 2) = (unsigned short)bf16r(w1r[i]);
            }
        }
        for (int e = tid; e < 64 * 16; e += NT) {             // W1T pads = 0
            int l = e >> 4, d = e & 15;
            *(unsigned*)(LDS + LS_BUF2 + l * 464 + 400 + d * 4) = 0;
        }
        if (s == 0) {                         // W2T/B1/B2: staged once, never overwritten
#pragma unroll
            for (int i = 0; i < 4; ++i) {
                int e = tid + i * 1024;
                int k = e >> 6, l = e & 63;
                *(unsigned short*)(LDS + LS_W2T + l * 144 + k * 2) = (unsigned short)bf16r(w2r[i]);
            }
            if (tid < 64) *(float*)(LDS + LS_B1 + tid * 4) = b1f[tid];
            else if (tid < 128) *(float*)(LDS + LS_B2 + (tid - 64) * 4) = b2f[tid - 64];
        }

        if (tid < 800) *(float*)(LDS + LS_MUS + tid * 4) = mu0;   // slot q0*200+n0 == tid
        if (diag0) {
#pragma unroll
            for (int r = 0; r < 16; ++r) {
                int rowin = (r & 3) + 8 * (r >> 2) + 4 * hi32;
                int n = ti * 32 + rowin;
                if (l31 == rowin && n < 200)
                    *(float*)(LDS + LS_VARA + n * 4) = acc0[r];   // S_nn
            }
        }
        BAR_LDS();

        // ---- per-node mu, rs ----
        if (tid < 200) {
            float sm = *(const float*)(LDS + LS_MUS + tid * 4)
                     + *(const float*)(LDS + LS_MUS + 800 + tid * 4)
                     + *(const float*)(LDS + LS_MUS + 1600 + tid * 4)
                     + *(const float*)(LDS + LS_MUS + 2400 + tid * 4);
            float mu = sm * (1.f / 256.f);
            float var = *(const float*)(LDS + LS_VARA + tid * 4) - 256.f * mu * mu;
            *(float*)(LDS + LS_MUA + tid * 4) = mu;
            *(float*)(LDS + LS_RSA + tid * 4) = (var > 0.f) ? rsqrtf(var) : 0.f;
        }
        BAR_LDS();

        // ---- epilogue: |corr| -> image [200][232] bf16 (r11 symmetric-pack) ----
        unsigned short* A16 = (unsigned short*)LDS;
        auto epi = [&](const f32x16& ac, int ib, int jb) {
            int col = jb + l31;
            if (col < 200) {
                float muc = *(const float*)(LDS + LS_MUA + col * 4);
                float rsc = *(const float*)(LDS + LS_RSA + col * 4);
                unsigned short cv[16];
#pragma unroll
                for (int g = 0; g < 4; ++g) {
                    int rb = ib + 8 * g + 4 * hi32;       // quad base row (mult of 4)
                    float4 mur4 = *(const float4*)(LDS + LS_MUA + rb * 4);  // may read junk
                    float4 rsr4 = *(const float4*)(LDS + LS_RSA + rb * 4);  // (writes guarded)
                    cv[4*g+0] = (unsigned short)bf16r(fabsf((ac[4*g+0] - 256.f * mur4.x * muc) * (rsr4.x * rsc)));
                    cv[4*g+1] = (unsigned short)bf16r(fabsf((ac[4*g+1] - 256.f * mur4.y * muc) * (rsr4.y * rsc)));
                    cv[4*g+2] = (unsigned short)bf16r(fabsf((ac[4*g+2] - 256.f * mur4.z * muc) * (rsr4.z * rsc)));
                    cv[4*g+3] = (unsigned short)bf16r(fabsf((ac[4*g+3] - 256.f * mur4.w * muc) * (rsr4.w * rsc)));
                    if (rb < 200) {
                        uint2 uu;
                        uu.x = (unsigned)cv[4*g+0] | ((unsigned)cv[4*g+1] << 16);
                        uu.y = (unsigned)cv[4*g+2] | ((unsigned)cv[4*g+3] << 16);
                        *(uint2*)(LDS + col * 464 + rb * 2) = uu;   // image[col][rb..rb+3]
                    }
                }
                if (ib != jb) {
#pragma unroll
                    for (int r = 0; r < 16; ++r) {
                        int row = ib + (r & 3) + 8 * (r >> 2) + 4 * hi32;
                        if (row < 200) A16[row * ARS + col] = cv[r];
                    }
                }
            }
        };
        epi(acc0, ti * 32, tj0_ * 32);
        if (dual) epi(acc1, ti * 32, tj1_ * 32);
        for (int e = tid; e < 3200; e += NT) {            // image pad cols 200..231 = 0
            int row = e >> 4, pc = e & 15;
            *(unsigned*)(LDS + row * 464 + 400 + pc * 4) = 0;
        }
        BAR_LDS();                                        // stats dead from here on

        // ---- row sums -> dinv: 4 threads/row + shfl combine ----
        if (tid < 800) {
            int row = tid >> 2, part = tid & 3;
            int sl0 = part * 7, ns = (part == 3) ? 8 : 7;
            float sm = (part == 0) ? 1.f : 0.f;           // the +I
#pragma unroll
            for (int e2 = 0; e2 < 8; ++e2) {
                if (e2 < ns) {
                    short8 v = *(const short8*)(LDS + row * 464 + (sl0 + e2) * 16);
#pragma unroll
                    for (int j = 0; j < 8; ++j) sm += bf2f((unsigned short)v[j]);
                }
            }
            sm += __shfl_xor(sm, 1);
            sm += __shfl_xor(sm, 2);
            if (part == 0) *(float*)(LDS + LS_DINV + row * 4) = rsqrtf(sm);
        }
        for (int e = tid; e < 64 * 16; e += NT) {         // YT pads = 0 (stats now dead)
            int l = e >> 4, d = e & 15;
            *(unsigned*)(LDS + LS_YT + l * 464 + 400 + d * 4) = 0;
        }
        BAR_LDS();

        // ============ GCN: 32x32x16, 7 waves x (1 row-tile x BOTH col-tiles) ========
        const int tr = wid;
        const int gc0 = l31, gc1 = 32 + l31;
        int grow = tr * 32 + l31; if (grow > 199) grow = 199;

        // ---- G1: t1 = A @ W1; y = dinv*t1 -> YT[c][j] ----
        if (wid < 7) {
            f32x16 a0 = {}, a1 = {};
#pragma unroll
            for (int ch = 0; ch < 13; ++ch) {
                int kb = ch * 32 + hi32 * 16;
                short8 av = *(const short8*)(LDS + grow * 464 + kb);
                short8 bv0 = *(const short8*)(LDS + LS_BUF2 + gc0 * 464 + kb);
                short8 bv1 = *(const short8*)(LDS + LS_BUF2 + gc1 * 464 + kb);
                a0 = __builtin_amdgcn_mfma_f32_32x32x16_bf16(av, bv0, a0, 0, 0, 0);
                a1 = __builtin_amdgcn_mfma_f32_32x32x16_bf16(av, bv1, a1, 0, 0, 0);
            }
#pragma unroll
            for (int g = 0; g < 4; ++g) {
                int j0 = tr * 32 + 8 * g + 4 * hi32;
                if (j0 < 200) {
                    float4 dv4 = *(const float4*)(LDS + LS_DINV + j0 * 4);
                    uint2 u0, u1;
                    u0.x = bf16r(dv4.x * a0[4*g+0]) | (bf16r(dv4.y * a0[4*g+1]) << 16);
                    u0.y = bf16r(dv4.z * a0[4*g+2]) | (bf16r(dv4.w * a0[4*g+3]) << 16);
                    u1.x = bf16r(dv4.x * a1[4*g+0]) | (bf16r(dv4.y * a1[4*g+1]) << 16);
                    u1.y = bf16r(dv4.z * a1[4*g+2]) | (bf16r(dv4.w * a1[4*g+3]) << 16);
                    *(uint2*)(LDS + LS_YT + gc0 * 464 + j0 * 2) = u0;
                    *(uint2*)(LDS + LS_YT + gc1 * 464 + j0 * 2) = u1;
                }
            }
        }
        BAR_LDS();

        // ---- cross-sample prefetch: issue sample s+1's chunks 0/1 now; the loads
        // fly under G2+G3+G4 (BAR_LDS never drains vmcnt). Consumed at s+1 pack. ----
        if (s == 0) { ldchunk(dnext, 0, rA); ldchunk(dnext, 1, rB); }

        // ---- G2: z = A @ y; h = relu(dinv_i*(z + y_i) + b1) -> BUF2[i][c] ----
        if (wid < 7) {
            f32x16 a0 = {}, a1 = {};
#pragma unroll
            for (int ch = 0; ch < 13; ++ch) {
                int kb = ch * 32 + hi32 * 16;
                short8 av = *(const short8*)(LDS + grow * 464 + kb);
                short8 bv0 = *(const short8*)(LDS + LS_YT + gc0 * 464 + kb);
                short8 bv1 = *(const short8*)(LDS + LS_YT + gc1 * 464 + kb);
                a0 = __builtin_amdgcn_mfma_f32_32x32x16_bf16(av, bv0, a0, 0, 0, 0);
                a1 = __builtin_amdgcn_mfma_f32_32x32x16_bf16(av, bv1, a1, 0, 0, 0);
            }
            float bias0 = *(const float*)(LDS + LS_B1 + gc0 * 4);
            float bias1 = *(const float*)(LDS + LS_B1 + gc1 * 4);
#pragma unroll
            for (int g = 0; g < 4; ++g) {
                int i0 = tr * 32 + 8 * g + 4 * hi32;
                if (i0 < 200) {
                    float4 dv4 = *(const float4*)(LDS + LS_DINV + i0 * 4);
                    uint2 yv0 = *(const uint2*)(LDS + LS_YT + gc0 * 464 + i0 * 2);
                    uint2 yv1 = *(const uint2*)(LDS + LS_YT + gc1 * 464 + i0 * 2);
#pragma unroll
                    for (int q = 0; q < 4; ++q) {
                        float dq = (q == 0) ? dv4.x : (q == 1) ? dv4.y : (q == 2) ? dv4.z : dv4.w;
                        unsigned yw0 = (q < 2) ? yv0.x : yv0.y;
                        unsigned yw1 = (q < 2) ? yv1.x : yv1.y;
                        float y0 = bf2f((unsigned short)((q & 1) ? (yw0 >> 16) : (yw0 & 0xffff)));
                        float y1 = bf2f((unsigned short)((q & 1) ? (yw1 >> 16) : (yw1 & 0xffff)));
                        float v0 = fmaxf(dq * (a0[4*g+q] + y0) + bias0, 0.f);
                        float v1 = fmaxf(dq * (a1[4*g+q] + y1) + bias1, 0.f);
                        *(unsigned short*)(LDS + LS_BUF2 + (i0 + q) * 144 + gc0 * 2) = (unsigned short)bf16r(v0);
                        *(unsigned short*)(LDS + LS_BUF2 + (i0 + q) * 144 + gc1 * 2) = (unsigned short)bf16r(v1);
                    }
                }
            }
        }
        BAR_LDS();

        // ---- G3: t2 = h @ W2; y2 = dinv*t2 -> YT[c][j] (K = 64) ----
        if (wid < 7) {
            f32x16 a0 = {}, a1 = {};
#pragma unroll
            for (int ch = 0; ch < 4; ++ch) {
                int kb = ch * 32 + hi32 * 16;
                short8 av = *(const short8*)(LDS + LS_BUF2 + grow * 144 + kb);
                short8 bv0 = *(const short8*)(LDS + LS_W2T + gc0 * 144 + kb);
                short8 bv1 = *(const short8*)(LDS + LS_W2T + gc1 * 144 + kb);
                a0 = __builtin_amdgcn_mfma_f32_32x32x16_bf16(av, bv0, a0, 0, 0, 0);
                a1 = __builtin_amdgcn_mfma_f32_32x32x16_bf16(av, bv1, a1, 0, 0, 0);
            }
#pragma unroll
            for (int g = 0; g < 4; ++g) {
                int j0 = tr * 32 + 8 * g + 4 * hi32;
                if (j0 < 200) {
                    float4 dv4 = *(const float4*)(LDS + LS_DINV + j0 * 4);
                    uint2 u0, u1;
                    u0.x = bf16r(dv4.x * a0[4*g+0]) | (bf16r(dv4.y * a0[4*g+1]) << 16);
                    u0.y = bf16r(dv4.z * a0[4*g+2]) | (bf16r(dv4.w * a0[4*g+3]) << 16);
                    u1.x = bf16r(dv4.x * a1[4*g+0]) | (bf16r(dv4.y * a1[4*g+1]) << 16);
                    u1.y = bf16r(dv4.z * a1[4*g+2]) | (bf16r(dv4.w * a1[4*g+3]) << 16);
                    *(uint2*)(LDS + LS_YT + gc0 * 464 + j0 * 2) = u0;
                    *(uint2*)(LDS + LS_YT + gc1 * 464 + j0 * 2) = u1;
                }
            }
        }
        BAR_LDS();

        // ---- G4: z2 = A @ y2; out = relu(dinv_i*(z2 + y2_i) + b2) ----
        if (wid < 7) {
            f32x16 a0 = {}, a1 = {};
#pragma unroll
            for (int ch = 0; ch < 13; ++ch) {
                int kb = ch * 32 + hi32 * 16;
                short8 av = *(const short8*)(LDS + grow * 464 + kb);
                short8 bv0 = *(const short8*)(LDS + LS_YT + gc0 * 464 + kb);
                short8 bv1 = *(const short8*)(LDS + LS_YT + gc1 * 464 + kb);
                a0 = __builtin_amdgcn_mfma_f32_32x32x16_bf16(av, bv0, a0, 0, 0, 0);
                a1 = __builtin_amdgcn_mfma_f32_32x32x16_bf16(av, bv1, a1, 0, 0, 0);
            }
            float bias0 = *(const float*)(LDS + LS_B2 + gc0 * 4);
            float bias1 = *(const float*)(LDS + LS_B2 + gc1 * 4);
#pragma unroll
            for (int g = 0; g < 4; ++g) {
                int i0 = tr * 32 + 8 * g + 4 * hi32;
                if (i0 < 200) {
                    float4 dv4 = *(const float4*)(LDS + LS_DINV + i0 * 4);
                    uint2 yv0 = *(const uint2*)(LDS + LS_YT + gc0 * 464 + i0 * 2);
                    uint2 yv1 = *(const uint2*)(LDS + LS_YT + gc1 * 464 + i0 * 2);
                    float* ob = obase + (size_t)i0 * H;
#pragma unroll
                    for (int q = 0; q < 4; ++q) {
                        float dq = (q == 0) ? dv4.x : (q == 1) ? dv4.y : (q == 2) ? dv4.z : dv4.w;
                        unsigned yw0 = (q < 2) ? yv0.x : yv0.y;
                        unsigned yw1 = (q < 2) ? yv1.x : yv1.y;
                        float y0 = bf2f((unsigned short)((q & 1) ? (yw0 >> 16) : (yw0 & 0xffff)));
                        float y1 = bf2f((unsigned short)((q & 1) ? (yw1 >> 16) : (yw1 & 0xffff)));
                        ob[q * H + gc0] = fmaxf(dq * (a0[4*g+q] + y0) + bias0, 0.f);
                        ob[q * H + gc1] = fmaxf(dq * (a1[4*g+q] + y1) + bias1, 0.f);
                    }
                }
            }
        }
        // s=1's pack writes Xt0/Xt1 which overlap YT/BUF2 (read by G3/G4):
        // seal sample s's LDS reads before the next corr loop.
        if (s == 0) BAR_LDS();
    }
}

extern "C" void kernel_launch(void* const* d_in, const int* in_sizes, int n_in,
                              void* d_out, int out_size, void* d_ws, size_t ws_size,
                              hipStream_t stream) {
    const float* data = (const float*)d_in[0];
    const float* W1   = (const float*)d_in[1];
    const float* b1   = (const float*)d_in[2];
    const float* W2   = (const float*)d_in[3];
    const float* b2   = (const float*)d_in[4];
    float* out = (float*)d_out;

    hipLaunchKernelGGL(k_fused, dim3(B / 2), dim3(NT), 0, stream, data, W1, b1, W2, b2, out);
}

// Round 16
// 103.348 us; speedup vs baseline: 1.0833x; 1.0833x over previous
//
#include <hip/hip_runtime.h>
#include <math.h>

#define B 512
#define T 256
#define N 200
#define H 64
#define TN (T*N)     // 51200
#define NT 1024      // 16 waves -> 4 waves/SIMD

#define ARS 232              // A image row stride in bf16 (464 B)
#define XTRS 80              // Xt row stride bytes (32 bf16 + 16B pad; 5 slots, odd -> skew)

// ---- LDS map (byte offsets), liveness-sequenced (proven r9-r14) ----
#define LS_XT(i) (102400 + 16000*(i))   // 2 x [200 n][32 t] bf16 stride 80
#define LS_MUS   92800                  // 800 f32 mu partials
#define LS_VARA  96000                  // 200 f32 raw diag
#define LS_MUA   96800
#define LS_RSA   97600                  // ..98400
#define LS_YT    92800                  // 64 x 464 B  (pads zeroed AFTER stats die)
#define LS_BUF2  122496                 // 64 x 464 B  (W1T, then h; overlaps dead Xt1)
#define LS_W2T   152192                 // 64 x 144 B  (staged ONCE, never overwritten)
#define LS_DINV  161408                 // 200 f32 (per-sample)
#define LS_B1    162208
#define LS_B2    162464
#define LS_SZ    162720

typedef short short8 __attribute__((ext_vector_type(8)));
typedef float f32x16 __attribute__((ext_vector_type(16)));

__device__ __forceinline__ unsigned bf16r(float x) {
    unsigned u = __float_as_uint(x);
    return (u + 0x7fffu + ((u >> 16) & 1u)) >> 16;   // round-to-nearest-even
}
__device__ __forceinline__ float bf2f(unsigned short u) {
    return __uint_as_float(((unsigned)u) << 16);
}

// LDS-only barrier: does NOT drain vmcnt, so global prefetch loads issued
// before it stay in flight (cross-sample pipeline).
#define BAR_LDS() do { \
    asm volatile("s_waitcnt lgkmcnt(0)" ::: "memory"); \
    __builtin_amdgcn_sched_barrier(0); \
    __builtin_amdgcn_s_barrier(); \
    __builtin_amdgcn_sched_barrier(0); } while (0)

// __launch_bounds__(1024, 4): 4 waves/EU == 1 block/CU (the LDS-forced occupancy).
// WITHOUT the 2nd arg the compiler capped VGPR at 64 and spilled ~180 MB of
// scratch per dispatch (r15 regression: WRITE 25.6->141 MB). With it: cap 128.
__global__ __launch_bounds__(NT, 4) void k_fused(const float* __restrict__ data,
                                                 const float* __restrict__ W1,
                                                 const float* __restrict__ b1f,
                                                 const float* __restrict__ W2,
                                                 const float* __restrict__ b2f,
                                                 float* __restrict__ out) {
    __shared__ __align__(16) unsigned char LDS[LS_SZ];
    const int tid  = threadIdx.x;
    const int blk  = blockIdx.x;        // grid = 256; block handles samples 2*blk, 2*blk+1
    const int lane = tid & 63;
    const int wid  = tid >> 6;          // 0..15
    const int l31  = lane & 31;
    const int hi32 = lane >> 5;

    float rA[8], rB[8];                 // register chunk buffers (no LDS staging)
    const int n0 = tid % 200, q0 = tid / 200;   // transpose unit (tid<800 only)

    // ---- corr tile assignment: 28 upper-tri tiles = 12 A-sharing pairs + 4 singles ----
    int ti, tj0_; bool dual;
    if      (wid == 0)  { ti = 0; tj0_ = 0; dual = true;  }
    else if (wid == 1)  { ti = 0; tj0_ = 2; dual = true;  }
    else if (wid == 2)  { ti = 0; tj0_ = 4; dual = true;  }
    else if (wid == 3)  { ti = 1; tj0_ = 1; dual = true;  }
    else if (wid == 4)  { ti = 1; tj0_ = 3; dual = true;  }
    else if (wid == 5)  { ti = 1; tj0_ = 5; dual = true;  }
    else if (wid == 6)  { ti = 2; tj0_ = 2; dual = true;  }
    else if (wid == 7)  { ti = 2; tj0_ = 4; dual = true;  }
    else if (wid == 8)  { ti = 3; tj0_ = 3; dual = true;  }
    else if (wid == 9)  { ti = 3; tj0_ = 5; dual = true;  }
    else if (wid == 10) { ti = 4; tj0_ = 4; dual = true;  }
    else if (wid == 11) { ti = 5; tj0_ = 5; dual = true;  }
    else if (wid == 12) { ti = 0; tj0_ = 6; dual = false; }
    else if (wid == 13) { ti = 2; tj0_ = 6; dual = false; }
    else if (wid == 14) { ti = 4; tj0_ = 6; dual = false; }
    else                { ti = 6; tj0_ = 6; dual = false; }
    const int tj1_ = tj0_ + 1;
    const bool diag0 = (ti == tj0_);
    int arow = ti * 32 + l31;   if (arow > 199) arow = 199;
    int bc0  = tj0_ * 32 + l31; if (bc0 > 199)  bc0 = 199;
    int bc1  = tj1_ * 32 + l31; if (bc1 > 199)  bc1 = 199;

    auto ldchunk = [&](const float* base, int cc, float* r) {
        if (tid < 800) {
            const float* src = base + (cc * 32 + q0 * 8) * 200 + n0;
#pragma unroll
            for (int j = 0; j < 8; ++j) r[j] = src[j * 200];
        }
    };

    const float* db0 = data + (size_t)(2 * blk) * TN;
    ldchunk(db0, 0, rA); ldchunk(db0, 1, rB);

    for (int s = 0; s < 2; ++s) {
        const float* dbase = data + (size_t)(2 * blk + s) * TN;
        const float* dnext = dbase + TN;                   // sample s+1 (s==0 only)
        float* obase = out + (size_t)(2 * blk + s) * N * H;

        f32x16 acc0 = {}, acc1 = {};
        float mu0 = 0.f;
        float w1r[13], w2r[4];          // short-lived: corr-tail -> weight staging

        auto pack = [&](int c, const float* r) {
            if (tid < 800) {
                unsigned u[4]; float a = 0.f;
#pragma unroll
                for (int j = 0; j < 4; ++j) {
                    unsigned b0 = bf16r(r[2 * j]);
                    unsigned b1 = bf16r(r[2 * j + 1]);
                    a += bf2f((unsigned short)b0) + bf2f((unsigned short)b1);
                    u[j] = b0 | (b1 << 16);
                }
                mu0 += a;
                uint4 pk; pk.x = u[0]; pk.y = u[1]; pk.z = u[2]; pk.w = u[3];
                *(uint4*)(LDS + LS_XT(c & 1) + n0 * XTRS + q0 * 16) = pk;
            }
        };
        auto domfma = [&](int cp) {
            const unsigned char* Xp = LDS + LS_XT(cp & 1);
#pragma unroll
            for (int kc = 0; kc < 2; ++kc) {
                int kb = kc * 32 + hi32 * 16;
                short8 a = *(const short8*)(Xp + arow * XTRS + kb);
                short8 b0 = diag0 ? a : *(const short8*)(Xp + bc0 * XTRS + kb);
                acc0 = __builtin_amdgcn_mfma_f32_32x32x16_bf16(a, b0, acc0, 0, 0, 0);
                if (dual) {
                    short8 b1 = *(const short8*)(Xp + bc1 * XTRS + kb);
                    acc1 = __builtin_amdgcn_mfma_f32_32x32x16_bf16(a, b1, acc1, 0, 0, 0);
                }
            }
        };

        // ---- corr K-loop: ONE barrier/chunk; region = {pack(c); issue(c+2); mfma(c)} ----
#pragma unroll
        for (int c = 0; c < 8; ++c) {
            if (c & 1) pack(c, rB); else pack(c, rA);
            if (c < 6) { if (c & 1) ldchunk(dbase, c + 2, rB); else ldchunk(dbase, c + 2, rA); }
            if (c == 7) {                    // per-sample weight prefetch (r14 pattern:
#pragma unroll                               // overlaps mfma(7)+tail, consumed right after)
                for (int i = 0; i < 12; ++i) w1r[i] = W1[tid + i * 1024];
                if (tid < 512) w1r[12] = W1[tid + 12288];
                if (s == 0) {
#pragma unroll
                    for (int i = 0; i < 4; ++i) w2r[i] = W2[tid + i * 1024];
                }
            }
            BAR_LDS();                       // publish Xt[c&1]
            domfma(c);
        }
        BAR_LDS();                           // Xt dead -> BUF2 (overlaps Xt1) writable

        // ---- weight staging (from regs) + mu partials + raw diag ----
#pragma unroll
        for (int i = 0; i < 13; ++i) {       // W1T -> BUF2 (re-staged per sample)
            int e = tid + i * 1024;
            if (i < 12 || tid < 512) {
                int k = e >> 6, l = e & 63;
                *(unsigned short*)(LDS + LS_BUF2 + l * 464 + k * 2) = (unsigned short)bf16r(w1r[i]);
            }
        }
        for (int e = tid; e < 64 * 16; e += NT) {             // W1T pads = 0
            int l = e >> 4, d = e & 15;
            *(unsigned*)(LDS + LS_BUF2 + l * 464 + 400 + d * 4) = 0;
        }
        if (s == 0) {                         // W2T/B1/B2: staged once, never overwritten
#pragma unroll
            for (int i = 0; i < 4; ++i) {
                int e = tid + i * 1024;
                int k = e >> 6, l = e & 63;
                *(unsigned short*)(LDS + LS_W2T + l * 144 + k * 2) = (unsigned short)bf16r(w2r[i]);
            }
            if (tid < 64) *(float*)(LDS + LS_B1 + tid * 4) = b1f[tid];
            else if (tid < 128) *(float*)(LDS + LS_B2 + (tid - 64) * 4) = b2f[tid - 64];
        }

        if (tid < 800) *(float*)(LDS + LS_MUS + tid * 4) = mu0;   // slot q0*200+n0 == tid
        if (diag0) {
#pragma unroll
            for (int r = 0; r < 16; ++r) {
                int rowin = (r & 3) + 8 * (r >> 2) + 4 * hi32;
                int n = ti * 32 + rowin;
                if (l31 == rowin && n < 200)
                    *(float*)(LDS + LS_VARA + n * 4) = acc0[r];   // S_nn
            }
        }
        BAR_LDS();

        // ---- per-node mu, rs ----
        if (tid < 200) {
            float sm = *(const float*)(LDS + LS_MUS + tid * 4)
                     + *(const float*)(LDS + LS_MUS + 800 + tid * 4)
                     + *(const float*)(LDS + LS_MUS + 1600 + tid * 4)
                     + *(const float*)(LDS + LS_MUS + 2400 + tid * 4);
            float mu = sm * (1.f / 256.f);
            float var = *(const float*)(LDS + LS_VARA + tid * 4) - 256.f * mu * mu;
            *(float*)(LDS + LS_MUA + tid * 4) = mu;
            *(float*)(LDS + LS_RSA + tid * 4) = (var > 0.f) ? rsqrtf(var) : 0.f;
        }
        BAR_LDS();

        // ---- epilogue: |corr| -> image [200][232] bf16 (r11 symmetric-pack) ----
        unsigned short* A16 = (unsigned short*)LDS;
        auto epi = [&](const f32x16& ac, int ib, int jb) {
            int col = jb + l31;
            if (col < 200) {
                float muc = *(const float*)(LDS + LS_MUA + col * 4);
                float rsc = *(const float*)(LDS + LS_RSA + col * 4);
                unsigned short cv[16];
#pragma unroll
                for (int g = 0; g < 4; ++g) {
                    int rb = ib + 8 * g + 4 * hi32;       // quad base row (mult of 4)
                    float4 mur4 = *(const float4*)(LDS + LS_MUA + rb * 4);  // may read junk
                    float4 rsr4 = *(const float4*)(LDS + LS_RSA + rb * 4);  // (writes guarded)
                    cv[4*g+0] = (unsigned short)bf16r(fabsf((ac[4*g+0] - 256.f * mur4.x * muc) * (rsr4.x * rsc)));
                    cv[4*g+1] = (unsigned short)bf16r(fabsf((ac[4*g+1] - 256.f * mur4.y * muc) * (rsr4.y * rsc)));
                    cv[4*g+2] = (unsigned short)bf16r(fabsf((ac[4*g+2] - 256.f * mur4.z * muc) * (rsr4.z * rsc)));
                    cv[4*g+3] = (unsigned short)bf16r(fabsf((ac[4*g+3] - 256.f * mur4.w * muc) * (rsr4.w * rsc)));
                    if (rb < 200) {
                        uint2 uu;
                        uu.x = (unsigned)cv[4*g+0] | ((unsigned)cv[4*g+1] << 16);
                        uu.y = (unsigned)cv[4*g+2] | ((unsigned)cv[4*g+3] << 16);
                        *(uint2*)(LDS + col * 464 + rb * 2) = uu;   // image[col][rb..rb+3]
                    }
                }
                if (ib != jb) {
#pragma unroll
                    for (int r = 0; r < 16; ++r) {
                        int row = ib + (r & 3) + 8 * (r >> 2) + 4 * hi32;
                        if (row < 200) A16[row * ARS + col] = cv[r];
                    }
                }
            }
        };
        epi(acc0, ti * 32, tj0_ * 32);
        if (dual) epi(acc1, ti * 32, tj1_ * 32);
        for (int e = tid; e < 3200; e += NT) {            // image pad cols 200..231 = 0
            int row = e >> 4, pc = e & 15;
            *(unsigned*)(LDS + row * 464 + 400 + pc * 4) = 0;
        }
        BAR_LDS();                                        // stats dead from here on

        // ---- row sums -> dinv: 4 threads/row + shfl combine ----
        if (tid < 800) {
            int row = tid >> 2, part = tid & 3;
            int sl0 = part * 7, ns = (part == 3) ? 8 : 7;
            float sm = (part == 0) ? 1.f : 0.f;           // the +I
#pragma unroll
            for (int e2 = 0; e2 < 8; ++e2) {
                if (e2 < ns) {
                    short8 v = *(const short8*)(LDS + row * 464 + (sl0 + e2) * 16);
#pragma unroll
                    for (int j = 0; j < 8; ++j) sm += bf2f((unsigned short)v[j]);
                }
            }
            sm += __shfl_xor(sm, 1);
            sm += __shfl_xor(sm, 2);
            if (part == 0) *(float*)(LDS + LS_DINV + row * 4) = rsqrtf(sm);
        }
        for (int e = tid; e < 64 * 16; e += NT) {         // YT pads = 0 (stats now dead)
            int l = e >> 4, d = e & 15;
            *(unsigned*)(LDS + LS_YT + l * 464 + 400 + d * 4) = 0;
        }
        BAR_LDS();

        // ============ GCN: 32x32x16, 7 waves x (1 row-tile x BOTH col-tiles) ========
        const int tr = wid;
        const int gc0 = l31, gc1 = 32 + l31;
        int grow = tr * 32 + l31; if (grow > 199) grow = 199;

        // ---- G1: t1 = A @ W1; y = dinv*t1 -> YT[c][j] ----
        if (wid < 7) {
            f32x16 a0 = {}, a1 = {};
#pragma unroll
            for (int ch = 0; ch < 13; ++ch) {
                int kb = ch * 32 + hi32 * 16;
                short8 av = *(const short8*)(LDS + grow * 464 + kb);
                short8 bv0 = *(const short8*)(LDS + LS_BUF2 + gc0 * 464 + kb);
                short8 bv1 = *(const short8*)(LDS + LS_BUF2 + gc1 * 464 + kb);
                a0 = __builtin_amdgcn_mfma_f32_32x32x16_bf16(av, bv0, a0, 0, 0, 0);
                a1 = __builtin_amdgcn_mfma_f32_32x32x16_bf16(av, bv1, a1, 0, 0, 0);
            }
#pragma unroll
            for (int g = 0; g < 4; ++g) {
                int j0 = tr * 32 + 8 * g + 4 * hi32;
                if (j0 < 200) {
                    float4 dv4 = *(const float4*)(LDS + LS_DINV + j0 * 4);
                    uint2 u0, u1;
                    u0.x = bf16r(dv4.x * a0[4*g+0]) | (bf16r(dv4.y * a0[4*g+1]) << 16);
                    u0.y = bf16r(dv4.z * a0[4*g+2]) | (bf16r(dv4.w * a0[4*g+3]) << 16);
                    u1.x = bf16r(dv4.x * a1[4*g+0]) | (bf16r(dv4.y * a1[4*g+1]) << 16);
                    u1.y = bf16r(dv4.z * a1[4*g+2]) | (bf16r(dv4.w * a1[4*g+3]) << 16);
                    *(uint2*)(LDS + LS_YT + gc0 * 464 + j0 * 2) = u0;
                    *(uint2*)(LDS + LS_YT + gc1 * 464 + j0 * 2) = u1;
                }
            }
        }
        BAR_LDS();

        // ---- cross-sample prefetch: sample s+1's chunks 0/1 fly under G2+G3+G4
        // (BAR_LDS never drains vmcnt); consumed at s+1's pack(0)/pack(1). ----
        if (s == 0) { ldchunk(dnext, 0, rA); ldchunk(dnext, 1, rB); }

        // ---- G2: z = A @ y; h = relu(dinv_i*(z + y_i) + b1) -> BUF2[i][c] ----
        if (wid < 7) {
            f32x16 a0 = {}, a1 = {};
#pragma unroll
            for (int ch = 0; ch < 13; ++ch) {
                int kb = ch * 32 + hi32 * 16;
                short8 av = *(const short8*)(LDS + grow * 464 + kb);
                short8 bv0 = *(const short8*)(LDS + LS_YT + gc0 * 464 + kb);
                short8 bv1 = *(const short8*)(LDS + LS_YT + gc1 * 464 + kb);
                a0 = __builtin_amdgcn_mfma_f32_32x32x16_bf16(av, bv0, a0, 0, 0, 0);
                a1 = __builtin_amdgcn_mfma_f32_32x32x16_bf16(av, bv1, a1, 0, 0, 0);
            }
            float bias0 = *(const float*)(LDS + LS_B1 + gc0 * 4);
            float bias1 = *(const float*)(LDS + LS_B1 + gc1 * 4);
#pragma unroll
            for (int g = 0; g < 4; ++g) {
                int i0 = tr * 32 + 8 * g + 4 * hi32;
                if (i0 < 200) {
                    float4 dv4 = *(const float4*)(LDS + LS_DINV + i0 * 4);
                    uint2 yv0 = *(const uint2*)(LDS + LS_YT + gc0 * 464 + i0 * 2);
                    uint2 yv1 = *(const uint2*)(LDS + LS_YT + gc1 * 464 + i0 * 2);
#pragma unroll
                    for (int q = 0; q < 4; ++q) {
                        float dq = (q == 0) ? dv4.x : (q == 1) ? dv4.y : (q == 2) ? dv4.z : dv4.w;
                        unsigned yw0 = (q < 2) ? yv0.x : yv0.y;
                        unsigned yw1 = (q < 2) ? yv1.x : yv1.y;
                        float y0 = bf2f((unsigned short)((q & 1) ? (yw0 >> 16) : (yw0 & 0xffff)));
                        float y1 = bf2f((unsigned short)((q & 1) ? (yw1 >> 16) : (yw1 & 0xffff)));
                        float v0 = fmaxf(dq * (a0[4*g+q] + y0) + bias0, 0.f);
                        float v1 = fmaxf(dq * (a1[4*g+q] + y1) + bias1, 0.f);
                        *(unsigned short*)(LDS + LS_BUF2 + (i0 + q) * 144 + gc0 * 2) = (unsigned short)bf16r(v0);
                        *(unsigned short*)(LDS + LS_BUF2 + (i0 + q) * 144 + gc1 * 2) = (unsigned short)bf16r(v1);
                    }
                }
            }
        }
        BAR_LDS();

        // ---- G3: t2 = h @ W2; y2 = dinv*t2 -> YT[c][j] (K = 64) ----
        if (wid < 7) {
            f32x16 a0 = {}, a1 = {};
#pragma unroll
            for (int ch = 0; ch < 4; ++ch) {
                int kb = ch * 32 + hi32 * 16;
                short8 av = *(const short8*)(LDS + LS_BUF2 + grow * 144 + kb);
                short8 bv0 = *(const short8*)(LDS + LS_W2T + gc0 * 144 + kb);
                short8 bv1 = *(const short8*)(LDS + LS_W2T + gc1 * 144 + kb);
                a0 = __builtin_amdgcn_mfma_f32_32x32x16_bf16(av, bv0, a0, 0, 0, 0);
                a1 = __builtin_amdgcn_mfma_f32_32x32x16_bf16(av, bv1, a1, 0, 0, 0);
            }
#pragma unroll
            for (int g = 0; g < 4; ++g) {
                int j0 = tr * 32 + 8 * g + 4 * hi32;
                if (j0 < 200) {
                    float4 dv4 = *(const float4*)(LDS + LS_DINV + j0 * 4);
                    uint2 u0, u1;
                    u0.x = bf16r(dv4.x * a0[4*g+0]) | (bf16r(dv4.y * a0[4*g+1]) << 16);
                    u0.y = bf16r(dv4.z * a0[4*g+2]) | (bf16r(dv4.w * a0[4*g+3]) << 16);
                    u1.x = bf16r(dv4.x * a1[4*g+0]) | (bf16r(dv4.y * a1[4*g+1]) << 16);
                    u1.y = bf16r(dv4.z * a1[4*g+2]) | (bf16r(dv4.w * a1[4*g+3]) << 16);
                    *(uint2*)(LDS + LS_YT + gc0 * 464 + j0 * 2) = u0;
                    *(uint2*)(LDS + LS_YT + gc1 * 464 + j0 * 2) = u1;
                }
            }
        }
        BAR_LDS();

        // ---- G4: z2 = A @ y2; out = relu(dinv_i*(z2 + y2_i) + b2) ----
        if (wid < 7) {
            f32x16 a0 = {}, a1 = {};
#pragma unroll
            for (int ch = 0; ch < 13; ++ch) {
                int kb = ch * 32 + hi32 * 16;
                short8 av = *(const short8*)(LDS + grow * 464 + kb);
                short8 bv0 = *(const short8*)(LDS + LS_YT + gc0 * 464 + kb);
                short8 bv1 = *(const short8*)(LDS + LS_YT + gc1 * 464 + kb);
                a0 = __builtin_amdgcn_mfma_f32_32x32x16_bf16(av, bv0, a0, 0, 0, 0);
                a1 = __builtin_amdgcn_mfma_f32_32x32x16_bf16(av, bv1, a1, 0, 0, 0);
            }
            float bias0 = *(const float*)(LDS + LS_B2 + gc0 * 4);
            float bias1 = *(const float*)(LDS + LS_B2 + gc1 * 4);
#pragma unroll
            for (int g = 0; g < 4; ++g) {
                int i0 = tr * 32 + 8 * g + 4 * hi32;
                if (i0 < 200) {
                    float4 dv4 = *(const float4*)(LDS + LS_DINV + i0 * 4);
                    uint2 yv0 = *(const uint2*)(LDS + LS_YT + gc0 * 464 + i0 * 2);
                    uint2 yv1 = *(const uint2*)(LDS + LS_YT + gc1 * 464 + i0 * 2);
                    float* ob = obase + (size_t)i0 * H;
#pragma unroll
                    for (int q = 0; q < 4; ++q) {
                        float dq = (q == 0) ? dv4.x : (q == 1) ? dv4.y : (q == 2) ? dv4.z : dv4.w;
                        unsigned yw0 = (q < 2) ? yv0.x : yv0.y;
                        unsigned yw1 = (q < 2) ? yv1.x : yv1.y;
                        float y0 = bf2f((unsigned short)((q & 1) ? (yw0 >> 16) : (yw0 & 0xffff)));
                        float y1 = bf2f((unsigned short)((q & 1) ? (yw1 >> 16) : (yw1 & 0xffff)));
                        ob[q * H + gc0] = fmaxf(dq * (a0[4*g+q] + y0) + bias0, 0.f);
                        ob[q * H + gc1] = fmaxf(dq * (a1[4*g+q] + y1) + bias1, 0.f);
                    }
                }
            }
        }
        // s=1's pack writes Xt0/Xt1 which overlap YT/BUF2 (read by G3/G4):
        // seal sample s's LDS reads before the next corr loop.
        if (s == 0) BAR_LDS();
    }
}

extern "C" void kernel_launch(void* const* d_in, const int* in_sizes, int n_in,
                              void* d_out, int out_size, void* d_ws, size_t ws_size,
                              hipStream_t stream) {
    const float* data = (const float*)d_in[0];
    const float* W1   = (const float*)d_in[1];
    const float* b1   = (const float*)d_in[2];
    const float* W2   = (const float*)d_in[3];
    const float* b2   = (const float*)d_in[4];
    float* out = (float*)d_out;

    hipLaunchKernelGGL(k_fused, dim3(B / 2), dim3(NT), 0, stream, data, W1, b1, W2, b2, out);
}

// Round 17
// 50.140 us; speedup vs baseline: 2.2329x; 2.0612x over previous
//
#include <hip/hip_runtime.h>
#include <math.h>

#define B 512
#define T 256
#define N 200
#define H 64
#define TN (T*N)     // 51200
#define NT 1024      // 16 waves -> 4 waves/SIMD

#define ARS 232              // A image row stride in bf16 (464 B)
#define XTRS 80              // Xt row stride bytes (32 bf16 + 16B pad; 5 slots, odd -> skew)

// ---- fused-kernel LDS map (byte offsets), sequenced by liveness ----
// corr phase: Xt0/Xt1 [102400,134400) + stats [92800,98400); region [0,92800)
//             untouched until the epilogue writes the A image there.
// gcn  phase: image [0,92800) | YT | BUF2(W1T->h) | W2T | DINV | B1 | B2
#define LS_XT(i) (102400 + 16000*(i))   // 2 x [200 n][32 t] bf16 stride 80
#define LS_MUS   92800                  // 800 f32 mu partials
#define LS_VARA  96000                  // 200 f32 raw diag
#define LS_MUA   96800
#define LS_RSA   97600                  // ..98400
#define LS_YT    92800                  // 64 x 464 B  (pads zeroed AFTER stats die)
#define LS_BUF2  122496                 // 64 x 464 B  (W1T, then h; overlaps dead Xt1)
#define LS_W2T   152192                 // 64 x 144 B
#define LS_DINV  161408                 // 200 f32
#define LS_B1    162208
#define LS_B2    162464
#define LS_SZ    162720

typedef short short8 __attribute__((ext_vector_type(8)));
typedef float f32x16 __attribute__((ext_vector_type(16)));

__device__ __forceinline__ unsigned bf16r(float x) {
    unsigned u = __float_as_uint(x);
    return (u + 0x7fffu + ((u >> 16) & 1u)) >> 16;   // round-to-nearest-even
}
__device__ __forceinline__ float bf2f(unsigned short u) {
    return __uint_as_float(((unsigned)u) << 16);
}

__global__ __launch_bounds__(NT) void k_fused(const float* __restrict__ data,
                                              const float* __restrict__ W1,
                                              const float* __restrict__ b1f,
                                              const float* __restrict__ W2,
                                              const float* __restrict__ b2f,
                                              float* __restrict__ out) {
    __shared__ __align__(16) unsigned char LDS[LS_SZ];
    const int tid  = threadIdx.x;
    const int b    = blockIdx.x;
    const int lane = tid & 63;
    const int wid  = tid >> 6;          // 0..15
    const int l31  = lane & 31;
    const int hi32 = lane >> 5;
    const float* dbase = data + (size_t)b * TN;

    f32x16 acc0 = {}, acc1 = {};
    float mu0 = 0.f;
    float w1r[13], w2r[4];              // tail weight prefetch (c==7)
    float rA[8], rB[8];                 // direct-register chunk buffers (no LDS staging)
    const int n0 = tid % 200, q0 = tid / 200;   // transpose unit (tid<800 only)

    // ---- corr tile assignment: 28 upper-tri tiles = 12 A-sharing pairs + 4 singles ----
    int ti, tj0_; bool dual;
    if      (wid == 0)  { ti = 0; tj0_ = 0; dual = true;  }
    else if (wid == 1)  { ti = 0; tj0_ = 2; dual = true;  }
    else if (wid == 2)  { ti = 0; tj0_ = 4; dual = true;  }
    else if (wid == 3)  { ti = 1; tj0_ = 1; dual = true;  }
    else if (wid == 4)  { ti = 1; tj0_ = 3; dual = true;  }
    else if (wid == 5)  { ti = 1; tj0_ = 5; dual = true;  }
    else if (wid == 6)  { ti = 2; tj0_ = 2; dual = true;  }
    else if (wid == 7)  { ti = 2; tj0_ = 4; dual = true;  }
    else if (wid == 8)  { ti = 3; tj0_ = 3; dual = true;  }
    else if (wid == 9)  { ti = 3; tj0_ = 5; dual = true;  }
    else if (wid == 10) { ti = 4; tj0_ = 4; dual = true;  }
    else if (wid == 11) { ti = 5; tj0_ = 5; dual = true;  }
    else if (wid == 12) { ti = 0; tj0_ = 6; dual = false; }
    else if (wid == 13) { ti = 2; tj0_ = 6; dual = false; }
    else if (wid == 14) { ti = 4; tj0_ = 6; dual = false; }
    else                { ti = 6; tj0_ = 6; dual = false; }
    const int tj1_ = tj0_ + 1;
    const bool diag0 = (ti == tj0_);
    int arow = ti * 32 + l31;   if (arow > 199) arow = 199;
    int bc0  = tj0_ * 32 + l31; if (bc0 > 199)  bc0 = 199;
    int bc1  = tj1_ * 32 + l31; if (bc1 > 199)  bc1 = 199;

    // load chunk cc straight into registers: 8 coalesced b32 loads per thread
    auto ldchunk = [&](int cc, float* r) {
        if (tid < 800) {
            const float* src = dbase + (cc * 32 + q0 * 8) * 200 + n0;
#pragma unroll
            for (int j = 0; j < 8; ++j) r[j] = src[j * 200];
        }
    };
    // pack chunk c from registers -> Xt[c&1] bf16 [200n][32t] (+ mu partial, same order)
    auto pack = [&](int c, const float* r) {
        if (tid < 800) {
            unsigned u[4]; float a = 0.f;
#pragma unroll
            for (int j = 0; j < 4; ++j) {
                unsigned b0 = bf16r(r[2 * j]);
                unsigned b1 = bf16r(r[2 * j + 1]);
                a += bf2f((unsigned short)b0) + bf2f((unsigned short)b1);
                u[j] = b0 | (b1 << 16);
            }
            mu0 += a;
            uint4 pk; pk.x = u[0]; pk.y = u[1]; pk.z = u[2]; pk.w = u[3];
            *(uint4*)(LDS + LS_XT(c & 1) + n0 * XTRS + q0 * 16) = pk;
        }
    };
    auto domfma = [&](int cp) {
        const unsigned char* Xp = LDS + LS_XT(cp & 1);
#pragma unroll
        for (int kc = 0; kc < 2; ++kc) {
            int kb = kc * 32 + hi32 * 16;
            short8 a = *(const short8*)(Xp + arow * XTRS + kb);
            short8 b0 = diag0 ? a : *(const short8*)(Xp + bc0 * XTRS + kb);
            acc0 = __builtin_amdgcn_mfma_f32_32x32x16_bf16(a, b0, acc0, 0, 0, 0);
            if (dual) {
                short8 b1 = *(const short8*)(Xp + bc1 * XTRS + kb);
                acc1 = __builtin_amdgcn_mfma_f32_32x32x16_bf16(a, b1, acc1, 0, 0, 0);
            }
        }
    };

    // ---- corr K-loop: register loads 2 regions ahead; ONE barrier per chunk.
    // Region between barriers = { pack(c) ; issue loads(c+2) ; mfma(c) }.
    // pack(c+1) writes Xt[(c+1)&1] == Xt[(c-1)&1], separated from mfma(c-1)'s
    // reads by barrier(c) (lgkmcnt(0) drains both reads and writes per wave).
    ldchunk(0, rA); ldchunk(1, rB);
#pragma unroll
    for (int c = 0; c < 8; ++c) {
        if (c & 1) pack(c, rB); else pack(c, rA);
        if (c < 6) { if (c & 1) ldchunk(c + 2, rB); else ldchunk(c + 2, rA); }
        if (c == 7) {                        // weight prefetch: overlaps mfma(7)+tail
#pragma unroll
            for (int i = 0; i < 12; ++i) w1r[i] = W1[tid + i * 1024];
            if (tid < 512) w1r[12] = W1[tid + 12288];
#pragma unroll
            for (int i = 0; i < 4; ++i) w2r[i] = W2[tid + i * 1024];
        }
        asm volatile("s_waitcnt lgkmcnt(0)" ::: "memory");
        __builtin_amdgcn_sched_barrier(0);
        __builtin_amdgcn_s_barrier();        // publish Xt[c&1]
        __builtin_amdgcn_sched_barrier(0);
        domfma(c);
    }
    asm volatile("s_waitcnt lgkmcnt(0)" ::: "memory");
    __builtin_amdgcn_sched_barrier(0);
    __builtin_amdgcn_s_barrier();            // Xt dead -> BUF2 (overlaps Xt1) writable
    __builtin_amdgcn_sched_barrier(0);

    // ---- weight staging (from prefetched regs) + mu partials + raw diag ----
#pragma unroll
    for (int i = 0; i < 13; ++i) {
        int e = tid + i * 1024;
        if (i < 12 || tid < 512) {
            int k = e >> 6, l = e & 63;
            *(unsigned short*)(LDS + LS_BUF2 + l * 464 + k * 2) = (unsigned short)bf16r(w1r[i]);
        }
    }
    for (int e = tid; e < 64 * 16; e += NT) {             // W1T pads = 0
        int l = e >> 4, d = e & 15;
        *(unsigned*)(LDS + LS_BUF2 + l * 464 + 400 + d * 4) = 0;
    }
#pragma unroll
    for (int i = 0; i < 4; ++i) {
        int e = tid + i * 1024;
        int k = e >> 6, l = e & 63;
        *(unsigned short*)(LDS + LS_W2T + l * 144 + k * 2) = (unsigned short)bf16r(w2r[i]);
    }
    if (tid < 64) *(float*)(LDS + LS_B1 + tid * 4) = b1f[tid];
    else if (tid < 128) *(float*)(LDS + LS_B2 + (tid - 64) * 4) = b2f[tid - 64];

    if (tid < 800) *(float*)(LDS + LS_MUS + tid * 4) = mu0;   // slot q0*200+n0 == tid
    if (diag0) {
#pragma unroll
        for (int r = 0; r < 16; ++r) {
            int rowin = (r & 3) + 8 * (r >> 2) + 4 * hi32;
            int n = ti * 32 + rowin;
            if (l31 == rowin && n < 200)
                *(float*)(LDS + LS_VARA + n * 4) = acc0[r];   // S_nn
        }
    }
    __syncthreads();

    // ---- per-node mu, rs ----
    if (tid < 200) {
        float s = *(const float*)(LDS + LS_MUS + tid * 4)
                + *(const float*)(LDS + LS_MUS + 800 + tid * 4)
                + *(const float*)(LDS + LS_MUS + 1600 + tid * 4)
                + *(const float*)(LDS + LS_MUS + 2400 + tid * 4);
        float mu = s * (1.f / 256.f);
        float var = *(const float*)(LDS + LS_VARA + tid * 4) - 256.f * mu * mu;
        *(float*)(LDS + LS_MUA + tid * 4) = mu;
        *(float*)(LDS + LS_RSA + tid * 4) = (var > 0.f) ? rsqrtf(var) : 0.f;
    }
    __syncthreads();

    // ---- epilogue: |corr| -> image [200][232] bf16 (packed transposed quads +
    // scalar off-diag region; MFMA tile bit-exact symmetric, r11 derivation) ----
    unsigned short* A16 = (unsigned short*)LDS;
    auto epi = [&](const f32x16& ac, int ib, int jb) {
        int col = jb + l31;
        if (col < 200) {
            float muc = *(const float*)(LDS + LS_MUA + col * 4);
            float rsc = *(const float*)(LDS + LS_RSA + col * 4);
            unsigned short cv[16];
#pragma unroll
            for (int g = 0; g < 4; ++g) {
                int rb = ib + 8 * g + 4 * hi32;           // quad base row (mult of 4)
                float4 mur4 = *(const float4*)(LDS + LS_MUA + rb * 4);  // may read junk
                float4 rsr4 = *(const float4*)(LDS + LS_RSA + rb * 4);  // (writes guarded)
                cv[4*g+0] = (unsigned short)bf16r(fabsf((ac[4*g+0] - 256.f * mur4.x * muc) * (rsr4.x * rsc)));
                cv[4*g+1] = (unsigned short)bf16r(fabsf((ac[4*g+1] - 256.f * mur4.y * muc) * (rsr4.y * rsc)));
                cv[4*g+2] = (unsigned short)bf16r(fabsf((ac[4*g+2] - 256.f * mur4.z * muc) * (rsr4.z * rsc)));
                cv[4*g+3] = (unsigned short)bf16r(fabsf((ac[4*g+3] - 256.f * mur4.w * muc) * (rsr4.w * rsc)));
                if (rb < 200) {
                    uint2 uu;
                    uu.x = (unsigned)cv[4*g+0] | ((unsigned)cv[4*g+1] << 16);
                    uu.y = (unsigned)cv[4*g+2] | ((unsigned)cv[4*g+3] << 16);
                    *(uint2*)(LDS + col * 464 + rb * 2) = uu;   // image[col][rb..rb+3]
                }
            }
            if (ib != jb) {
#pragma unroll
                for (int r = 0; r < 16; ++r) {
                    int row = ib + (r & 3) + 8 * (r >> 2) + 4 * hi32;
                    if (row < 200) A16[row * ARS + col] = cv[r];
                }
            }
        }
    };
    epi(acc0, ti * 32, tj0_ * 32);
    if (dual) epi(acc1, ti * 32, tj1_ * 32);
    for (int e = tid; e < 3200; e += NT) {                // image pad cols 200..231 = 0
        int row = e >> 4, pc = e & 15;
        *(unsigned*)(LDS + row * 464 + 400 + pc * 4) = 0;
    }
    __syncthreads();                                      // stats dead from here on

    // ---- row sums -> dinv: 4 threads/row + shfl combine ----
    if (tid < 800) {
        int row = tid >> 2, part = tid & 3;
        int sl0 = part * 7, ns = (part == 3) ? 8 : 7;
        float s = (part == 0) ? 1.f : 0.f;                // the +I
#pragma unroll
        for (int e2 = 0; e2 < 8; ++e2) {
            if (e2 < ns) {
                short8 v = *(const short8*)(LDS + row * 464 + (sl0 + e2) * 16);
#pragma unroll
                for (int j = 0; j < 8; ++j) s += bf2f((unsigned short)v[j]);
            }
        }
        s += __shfl_xor(s, 1);
        s += __shfl_xor(s, 2);
        if (part == 0) *(float*)(LDS + LS_DINV + row * 4) = rsqrtf(s);
    }
    for (int e = tid; e < 64 * 16; e += NT) {             // YT pads = 0 (stats now dead)
        int l = e >> 4, d = e & 15;
        *(unsigned*)(LDS + LS_YT + l * 464 + 400 + d * 4) = 0;
    }
    __syncthreads();

    // ============ GCN: 32x32x16 MFMA, 7 waves x (1 row-tile x BOTH col-tiles) ========
    const int tr = wid;                                   // row-tile (wid<7)
    const int gc0 = l31, gc1 = 32 + l31;                  // the two output channels
    int grow = tr * 32 + l31; if (grow > 199) grow = 199; // A-frag row (clamped dup)

    // ---- G1: t1 = A @ W1; y = dinv*t1 -> YT[c][j] ----
    if (wid < 7) {
        f32x16 a0 = {}, a1 = {};
#pragma unroll
        for (int ch = 0; ch < 13; ++ch) {
            int kb = ch * 32 + hi32 * 16;
            short8 av = *(const short8*)(LDS + grow * 464 + kb);
            short8 bv0 = *(const short8*)(LDS + LS_BUF2 + gc0 * 464 + kb);
            short8 bv1 = *(const short8*)(LDS + LS_BUF2 + gc1 * 464 + kb);
            a0 = __builtin_amdgcn_mfma_f32_32x32x16_bf16(av, bv0, a0, 0, 0, 0);
            a1 = __builtin_amdgcn_mfma_f32_32x32x16_bf16(av, bv1, a1, 0, 0, 0);
        }
#pragma unroll
        for (int g = 0; g < 4; ++g) {
            int j0 = tr * 32 + 8 * g + 4 * hi32;
            if (j0 < 200) {
                float4 dv4 = *(const float4*)(LDS + LS_DINV + j0 * 4);
                uint2 u0, u1;
                u0.x = bf16r(dv4.x * a0[4*g+0]) | (bf16r(dv4.y * a0[4*g+1]) << 16);
                u0.y = bf16r(dv4.z * a0[4*g+2]) | (bf16r(dv4.w * a0[4*g+3]) << 16);
                u1.x = bf16r(dv4.x * a1[4*g+0]) | (bf16r(dv4.y * a1[4*g+1]) << 16);
                u1.y = bf16r(dv4.z * a1[4*g+2]) | (bf16r(dv4.w * a1[4*g+3]) << 16);
                *(uint2*)(LDS + LS_YT + gc0 * 464 + j0 * 2) = u0;
                *(uint2*)(LDS + LS_YT + gc1 * 464 + j0 * 2) = u1;
            }
        }
    }
    __syncthreads();

    // ---- G2: z = A @ y; h = relu(dinv_i*(z + y_i) + b1) -> BUF2[i][c] ----
    if (wid < 7) {
        f32x16 a0 = {}, a1 = {};
#pragma unroll
        for (int ch = 0; ch < 13; ++ch) {
            int kb = ch * 32 + hi32 * 16;
            short8 av = *(const short8*)(LDS + grow * 464 + kb);
            short8 bv0 = *(const short8*)(LDS + LS_YT + gc0 * 464 + kb);
            short8 bv1 = *(const short8*)(LDS + LS_YT + gc1 * 464 + kb);
            a0 = __builtin_amdgcn_mfma_f32_32x32x16_bf16(av, bv0, a0, 0, 0, 0);
            a1 = __builtin_amdgcn_mfma_f32_32x32x16_bf16(av, bv1, a1, 0, 0, 0);
        }
        float bias0 = *(const float*)(LDS + LS_B1 + gc0 * 4);
        float bias1 = *(const float*)(LDS + LS_B1 + gc1 * 4);
#pragma unroll
        for (int g = 0; g < 4; ++g) {
            int i0 = tr * 32 + 8 * g + 4 * hi32;
            if (i0 < 200) {
                float4 dv4 = *(const float4*)(LDS + LS_DINV + i0 * 4);
                uint2 yv0 = *(const uint2*)(LDS + LS_YT + gc0 * 464 + i0 * 2);
                uint2 yv1 = *(const uint2*)(LDS + LS_YT + gc1 * 464 + i0 * 2);
#pragma unroll
                for (int q = 0; q < 4; ++q) {
                    float dq = (q == 0) ? dv4.x : (q == 1) ? dv4.y : (q == 2) ? dv4.z : dv4.w;
                    unsigned yw0 = (q < 2) ? yv0.x : yv0.y;
                    unsigned yw1 = (q < 2) ? yv1.x : yv1.y;
                    float y0 = bf2f((unsigned short)((q & 1) ? (yw0 >> 16) : (yw0 & 0xffff)));
                    float y1 = bf2f((unsigned short)((q & 1) ? (yw1 >> 16) : (yw1 & 0xffff)));
                    float v0 = fmaxf(dq * (a0[4*g+q] + y0) + bias0, 0.f);
                    float v1 = fmaxf(dq * (a1[4*g+q] + y1) + bias1, 0.f);
                    *(unsigned short*)(LDS + LS_BUF2 + (i0 + q) * 144 + gc0 * 2) = (unsigned short)bf16r(v0);
                    *(unsigned short*)(LDS + LS_BUF2 + (i0 + q) * 144 + gc1 * 2) = (unsigned short)bf16r(v1);
                }
            }
        }
    }
    __syncthreads();

    // ---- G3: t2 = h @ W2; y2 = dinv*t2 -> YT[c][j] (K = 64 = 4 chunks) ----
    if (wid < 7) {
        f32x16 a0 = {}, a1 = {};
#pragma unroll
        for (int ch = 0; ch < 4; ++ch) {
            int kb = ch * 32 + hi32 * 16;
            short8 av = *(const short8*)(LDS + LS_BUF2 + grow * 144 + kb);
            short8 bv0 = *(const short8*)(LDS + LS_W2T + gc0 * 144 + kb);
            short8 bv1 = *(const short8*)(LDS + LS_W2T + gc1 * 144 + kb);
            a0 = __builtin_amdgcn_mfma_f32_32x32x16_bf16(av, bv0, a0, 0, 0, 0);
            a1 = __builtin_amdgcn_mfma_f32_32x32x16_bf16(av, bv1, a1, 0, 0, 0);
        }
#pragma unroll
        for (int g = 0; g < 4; ++g) {
            int j0 = tr * 32 + 8 * g + 4 * hi32;
            if (j0 < 200) {
                float4 dv4 = *(const float4*)(LDS + LS_DINV + j0 * 4);
                uint2 u0, u1;
                u0.x = bf16r(dv4.x * a0[4*g+0]) | (bf16r(dv4.y * a0[4*g+1]) << 16);
                u0.y = bf16r(dv4.z * a0[4*g+2]) | (bf16r(dv4.w * a0[4*g+3]) << 16);
                u1.x = bf16r(dv4.x * a1[4*g+0]) | (bf16r(dv4.y * a1[4*g+1]) << 16);
                u1.y = bf16r(dv4.z * a1[4*g+2]) | (bf16r(dv4.w * a1[4*g+3]) << 16);
                *(uint2*)(LDS + LS_YT + gc0 * 464 + j0 * 2) = u0;
                *(uint2*)(LDS + LS_YT + gc1 * 464 + j0 * 2) = u1;
            }
        }
    }
    __syncthreads();

    // ---- G4: z2 = A @ y2; out = relu(dinv_i*(z2 + y2_i) + b2) ----
    if (wid < 7) {
        f32x16 a0 = {}, a1 = {};
#pragma unroll
        for (int ch = 0; ch < 13; ++ch) {
            int kb = ch * 32 + hi32 * 16;
            short8 av = *(const short8*)(LDS + grow * 464 + kb);
            short8 bv0 = *(const short8*)(LDS + LS_YT + gc0 * 464 + kb);
            short8 bv1 = *(const short8*)(LDS + LS_YT + gc1 * 464 + kb);
            a0 = __builtin_amdgcn_mfma_f32_32x32x16_bf16(av, bv0, a0, 0, 0, 0);
            a1 = __builtin_amdgcn_mfma_f32_32x32x16_bf16(av, bv1, a1, 0, 0, 0);
        }
        float bias0 = *(const float*)(LDS + LS_B2 + gc0 * 4);
        float bias1 = *(const float*)(LDS + LS_B2 + gc1 * 4);
#pragma unroll
        for (int g = 0; g < 4; ++g) {
            int i0 = tr * 32 + 8 * g + 4 * hi32;
            if (i0 < 200) {
                float4 dv4 = *(const float4*)(LDS + LS_DINV + i0 * 4);
                uint2 yv0 = *(const uint2*)(LDS + LS_YT + gc0 * 464 + i0 * 2);
                uint2 yv1 = *(const uint2*)(LDS + LS_YT + gc1 * 464 + i0 * 2);
                float* ob = out + ((size_t)b * N + i0) * H;
#pragma unroll
                for (int q = 0; q < 4; ++q) {
                    float dq = (q == 0) ? dv4.x : (q == 1) ? dv4.y : (q == 2) ? dv4.z : dv4.w;
                    unsigned yw0 = (q < 2) ? yv0.x : yv0.y;
                    unsigned yw1 = (q < 2) ? yv1.x : yv1.y;
                    float y0 = bf2f((unsigned short)((q & 1) ? (yw0 >> 16) : (yw0 & 0xffff)));
                    float y1 = bf2f((unsigned short)((q & 1) ? (yw1 >> 16) : (yw1 & 0xffff)));
                    ob[q * H + gc0] = fmaxf(dq * (a0[4*g+q] + y0) + bias0, 0.f);
                    ob[q * H + gc1] = fmaxf(dq * (a1[4*g+q] + y1) + bias1, 0.f);
                }
            }
        }
    }
}

extern "C" void kernel_launch(void* const* d_in, const int* in_sizes, int n_in,
                              void* d_out, int out_size, void* d_ws, size_t ws_size,
                              hipStream_t stream) {
    const float* data = (const float*)d_in[0];
    const float* W1   = (const float*)d_in[1];
    const float* b1   = (const float*)d_in[2];
    const float* W2   = (const float*)d_in[3];
    const float* b2   = (const float*)d_in[4];
    float* out = (float*)d_out;

    hipLaunchKernelGGL(k_fused, dim3(B), dim3(NT), 0, stream, data, W1, b1, W2, b2, out);
}